// Round 9
// baseline (316.900 us; speedup 1.0000x reference)
//
#include <hip/hip_runtime.h>

#define NUM_K   4096
#define CDIM    64
#define HWDIM   4096            // 64*64
#define NVEC    65536           // 16 * 64 * 64
#define CHW     (CDIM * HWDIM)  // 262144
#define KT      32              // codes per k-tile
#define NKT_SL  64              // k-tiles per slice (2048 codes)
#define NPAIR   (NKT_SL / 2)    // 32 barrier groups (2 tiles per barrier)
// rescue margin on biased s/2 scale: bf16-split budget 2e-3 (validated r4-r6)
// + 7-bit mask granularity q<=3.9e-3 (scores < 512) + slack
#define TAUH    6e-3f
#define SBIAS   128.0f          // score bias: s' = 128 + (wsq - 2 x.w)/2 > 0 always
#define XSTR    66              // xs stride in bf16 (33 dwords, odd -> conflict-free)

// ---- output layout (floats, concatenated in reference return order) ----
#define O_Q     0               // quantized_ste  [16,64,64,64] = 4194304
#define O_LOSS  4194304         // scalar
#define O_IDX   4194305         // encoding_indices [16,64,64] = 65536 (as float)
#define O_W     4259841         // new_weight   [4096,64] = 262144
#define O_CS    4521985         // new_cluster_size [4096]
#define O_EW    4526081         // new_ema_w    [4096,64] = 262144
// dw accumulator LIVES in O_EW: prep zeroes it, assign atomically accumulates,
// finalize reads dw[e] then overwrites with new_ema_w[e] (per-thread RAW, safe).

// ---- workspace layout (floats) ----  high-water 401920 floats = 1.6 MB
#define W_WSQ    0               // wsq/2 + SBIAS [4096]
#define W_CNT    4096            // counts [4096] (+ loss at 8192) zeroed by prep
#define W_LOSS   8192
#define W_ESUM   8193            // sum(ecs), written (not atomic) by prep block 0
#define W_KEY    8704            // u64 keys [2][65536] = 262144 floats (8B-aligned)
#define W_B2     270848          // float b2 [2][65536]

typedef unsigned long long u64;
typedef __bf16 bf16x8 __attribute__((ext_vector_type(8)));
typedef __bf16 bf16x2 __attribute__((ext_vector_type(2)));
typedef float  f32x4  __attribute__((ext_vector_type(4)));

__device__ __forceinline__ unsigned f2ord(float f) {
    unsigned u = __float_as_uint(f);
    return (u & 0x80000000u) ? ~u : (u | 0x80000000u);  // monotone for all floats
}
__device__ __forceinline__ unsigned umn(unsigned a, unsigned b) { return a < b ? a : b; }
__device__ __forceinline__ unsigned umx(unsigned a, unsigned b) { return a > b ? a : b; }

// Per codebook row: biased wsq/2 + SBIAS + bf16 hi/lo split copies. Also:
// zeroes counts+loss (ws) and the dw accumulator (O_EW region); block 0
// computes esum = sum(ecs) directly (no atomic -> no zero/add race).
__global__ void __launch_bounds__(256)
prep_kernel(const float* __restrict__ w, float* __restrict__ wsqh,
            __bf16* __restrict__ wh, __bf16* __restrict__ wl,
            float* __restrict__ zero4097, float* __restrict__ dwz,
            const float* __restrict__ ecs, float* __restrict__ esum) {
    __shared__ float red[256];
    int gid = blockIdx.x * 256 + threadIdx.x;
    if (gid < 4097) zero4097[gid] = 0.f;       // counts[4096] + loss
    dwz[gid] = 0.f;                            // 1024*256 == 262144 exactly

    int wv = threadIdx.x >> 6, lane = threadIdx.x & 63;
    int row = blockIdx.x * 4 + wv;
    float v = w[row * CDIM + lane];
    __bf16 h = (__bf16)v;
    __bf16 l = (__bf16)(v - (float)h);         // v - hi exact in fp32
    wh[row * CDIM + lane] = h;
    wl[row * CDIM + lane] = l;
    float sq = v * v;
#pragma unroll
    for (int m = 1; m < 64; m <<= 1) sq += __shfl_xor(sq, m, 64);
    if (lane == 0) wsqh[row] = 0.5f * sq + SBIAS;

    if (blockIdx.x == 0) {                     // esum reduction, one block
        float s = 0.f;
        for (int k = threadIdx.x; k < NUM_K; k += 256) s += ecs[k];
        red[threadIdx.x] = s;
        __syncthreads();
        for (int st = 128; st > 0; st >>= 1) {
            if (threadIdx.x < st) red[threadIdx.x] += red[threadIdx.x + st];
            __syncthreads();
        }
        if (threadIdx.x == 0) esum[0] = red[0];
    }
}

// Fused bf16x3-split MFMA GEMM + argmin, K-split into 2 slices (grid.y).
// Biased scores strictly positive -> raw float bits order-monotone; in-loop
// top-2 on packed u32 keys (score & ~0x7F) | tag, tag = kt*2+half.
// kt-PAIR unrolled: 2 tiles per barrier (32 barriers), B dbuf = 2x2 tiles
// (32 KB) overlaid on the xs staging region (33.8 KB high-water, 4 blocks/CU).
__global__ void __launch_bounds__(256, 4)
argmin_mfma(const float* __restrict__ x,
            const __bf16* __restrict__ wh_g, const __bf16* __restrict__ wl_g,
            const float* __restrict__ wsqh_g,
            u64* __restrict__ keys, float* __restrict__ b2s) {
    extern __shared__ __bf16 smem[];           // 33792 B
    __bf16* xs_h = smem;                       // [128*66]
    __bf16* xs_l = smem + 128 * XSTR;
    __bf16* bs   = smem;                       // overlay: [2 buf][2 tile][4096]

    int t = threadIdx.x, wv = t >> 6, lane = t & 63;
    int n0 = blockIdx.x * 128;
    int b = n0 >> 12, hw0 = n0 & (HWDIM - 1);
    int kbase = blockIdx.y * (NUM_K / 2);
    int slice = blockIdx.y;

    // 1) stage -x hi/lo; bf16x2 writes, lane-stride 33 dwords -> conflict-free
#pragma unroll
    for (int half = 0; half < 2; ++half) {
        int i = half * 64 + lane;
        const float* xb = x + b * CHW + hw0 + i;
#pragma unroll
        for (int j = 0; j < 8; ++j) {
            int c0 = wv * 16 + j * 2;
            float v0 = -xb[c0 * HWDIM];
            float v1 = -xb[(c0 + 1) * HWDIM];
            __bf16 h0 = (__bf16)v0, h1 = (__bf16)v1;
            bf16x2 hh = {h0, h1};
            bf16x2 ll = {(__bf16)(v0 - (float)h0), (__bf16)(v1 - (float)h1)};
            *(bf16x2*)(xs_h + i * XSTR + c0) = hh;
            *(bf16x2*)(xs_l + i * XSTR + c0) = ll;
        }
    }
    __syncthreads();

    int nn = lane & 15, q4 = lane >> 4;
    // 2) A-frags -> registers (one-time)
    bf16x8 ah[2][2], al[2][2];
#pragma unroll
    for (int m = 0; m < 2; ++m) {
        int id = wv * 32 + m * 16 + nn;
#pragma unroll
        for (int ch = 0; ch < 2; ++ch) {
            union { unsigned u[4]; bf16x8 v; } th, tl;
            const unsigned* ph = (const unsigned*)(xs_h + id * XSTR + (q4 + ch * 4) * 8);
            const unsigned* pl = (const unsigned*)(xs_l + id * XSTR + (q4 + ch * 4) * 8);
#pragma unroll
            for (int jj = 0; jj < 4; ++jj) { th.u[jj] = ph[jj]; tl.u[jj] = pl[jj]; }
            ah[m][ch] = th.v; al[m][ch] = tl.v;
        }
    }
    __syncthreads();   // all waves done reading xs -> LDS reusable for B tiles

    // B staging map: thread t writes LDS bytes t*16 (consecutive, conflict-free);
    // reads at (chunk*16+code)*8 elems -> consecutive 16B per lane group.
    int sr = t & 15, sj = (t >> 4) & 7, ss = (t >> 7) & 1;
    long goff = (long)(ss * 16 + sr) * 64 + sj * 8;

    // 3) stage pair 0 (tiles 0,1) into buffer 0
#pragma unroll
    for (int tau = 0; tau < 2; ++tau) {
        long g = (long)(kbase + tau * KT) * 64 + goff;
        *(bf16x8*)(bs + tau * 4096 + t * 8)        = *(const bf16x8*)(wh_g + g);
        *(bf16x8*)(bs + tau * 4096 + 2048 + t * 8) = *(const bf16x8*)(wl_g + g);
    }
    __syncthreads();

    unsigned b1k[8], b2k[8];
#pragma unroll
    for (int s = 0; s < 8; ++s) { b1k[s] = 0xFFFFFFFFu; b2k[s] = 0xFFFFFFFFu; }

    for (int kp = 0; kp < NPAIR; ++kp) {
        bf16x8 sth[2], stl[2];
        bool pre = (kp + 1 < NPAIR);
        if (pre) {   // global loads for next pair; latency spans both tiles' MFMA
#pragma unroll
            for (int tau = 0; tau < 2; ++tau) {
                long g = (long)(kbase + ((kp + 1) * 2 + tau) * KT) * 64 + goff;
                sth[tau] = *(const bf16x8*)(wh_g + g);
                stl[tau] = *(const bf16x8*)(wl_g + g);
            }
        }

#pragma unroll
        for (int tau = 0; tau < 2; ++tau) {
            int kt = kp * 2 + tau;
            const __bf16* base = bs + (kp & 1) * 8192 + tau * 4096;
            int k0 = kbase + kt * KT;
            float wA = wsqh_g[k0 + nn];            // biased table, L1-hot
            float wB = wsqh_g[k0 + 16 + nn];
            unsigned tA = (unsigned)(kt * 2), tB = (unsigned)(kt * 2 + 1);

            int o1 = (q4 * 16 + nn) * 8, o2 = ((q4 + 4) * 16 + nn) * 8;
            bf16x8 bh0A = *(const bf16x8*)(base + o1);
            bf16x8 bh1A = *(const bf16x8*)(base + o2);
            bf16x8 bh0B = *(const bf16x8*)(base + 1024 + o1);
            bf16x8 bh1B = *(const bf16x8*)(base + 1024 + o2);
            bf16x8 bl0A = *(const bf16x8*)(base + 2048 + o1);
            bf16x8 bl1A = *(const bf16x8*)(base + 2048 + o2);
            bf16x8 bl0B = *(const bf16x8*)(base + 3072 + o1);
            bf16x8 bl1B = *(const bf16x8*)(base + 3072 + o2);

#pragma unroll
            for (int m = 0; m < 2; ++m) {
                f32x4 accA = {wA, wA, wA, wA};     // acc = SBIAS + wsq/2 - dot > 0
                f32x4 accB = {wB, wB, wB, wB};
                accA = __builtin_amdgcn_mfma_f32_16x16x32_bf16(ah[m][0], bh0A, accA, 0, 0, 0);
                accA = __builtin_amdgcn_mfma_f32_16x16x32_bf16(ah[m][1], bh1A, accA, 0, 0, 0);
                accA = __builtin_amdgcn_mfma_f32_16x16x32_bf16(al[m][0], bh0A, accA, 0, 0, 0);
                accA = __builtin_amdgcn_mfma_f32_16x16x32_bf16(al[m][1], bh1A, accA, 0, 0, 0);
                accA = __builtin_amdgcn_mfma_f32_16x16x32_bf16(ah[m][0], bl0A, accA, 0, 0, 0);
                accA = __builtin_amdgcn_mfma_f32_16x16x32_bf16(ah[m][1], bl1A, accA, 0, 0, 0);
                accB = __builtin_amdgcn_mfma_f32_16x16x32_bf16(ah[m][0], bh0B, accB, 0, 0, 0);
                accB = __builtin_amdgcn_mfma_f32_16x16x32_bf16(ah[m][1], bh1B, accB, 0, 0, 0);
                accB = __builtin_amdgcn_mfma_f32_16x16x32_bf16(al[m][0], bh0B, accB, 0, 0, 0);
                accB = __builtin_amdgcn_mfma_f32_16x16x32_bf16(al[m][1], bh1B, accB, 0, 0, 0);
                accB = __builtin_amdgcn_mfma_f32_16x16x32_bf16(ah[m][0], bl0B, accB, 0, 0, 0);
                accB = __builtin_amdgcn_mfma_f32_16x16x32_bf16(ah[m][1], bl1B, accB, 0, 0, 0);
#pragma unroll
                for (int r = 0; r < 4; ++r) {
                    unsigned ka = (__float_as_uint(accA[r]) & 0xFFFFFF80u) | tA;
                    unsigned kb = (__float_as_uint(accB[r]) & 0xFFFFFF80u) | tB;
                    unsigned lo = umn(ka, kb), hi = umx(ka, kb);
                    int s8 = m * 4 + r;
                    b2k[s8] = umn(umn(b2k[s8], umx(b1k[s8], lo)), hi);
                    b1k[s8] = umn(b1k[s8], lo);
                }
            }
        }
        if (pre) {
            __bf16* nb = bs + ((kp + 1) & 1) * 8192;
#pragma unroll
            for (int tau = 0; tau < 2; ++tau) {
                *(bf16x8*)(nb + tau * 4096 + t * 8)        = sth[tau];
                *(bf16x8*)(nb + tau * 4096 + 2048 + t * 8) = stl[tau];
            }
        }
        __syncthreads();
    }

    // unpack: tag*16 == kt*32 + half*16, so code = (kbase+nn) + tag*16
    float s1[8], sb2[8]; int code[8];
#pragma unroll
    for (int s = 0; s < 8; ++s) {
        s1[s]  = __uint_as_float(b1k[s] & 0xFFFFFF80u);
        sb2[s] = __uint_as_float(b2k[s] & 0xFFFFFF80u);
        code[s] = (kbase + nn) + (int)(b1k[s] & 0x7Fu) * 16;
    }
    // cross-lane merge over the 16 code-classes (lanes sharing q4)
#pragma unroll
    for (int msk = 1; msk < 16; msk <<= 1) {
#pragma unroll
        for (int s = 0; s < 8; ++s) {
            float os1 = __shfl_xor(s1[s], msk, 64);
            float ob2 = __shfl_xor(sb2[s], msk, 64);
            int   oc  = __shfl_xor(code[s], msk, 64);
            sb2[s] = fminf(fminf(sb2[s], ob2), fmaxf(s1[s], os1));
            if (os1 < s1[s]) code[s] = oc;   // exact ties -> margin 0 -> rescued
            s1[s] = fminf(s1[s], os1);
        }
    }
    if (nn == 0) {
#pragma unroll
        for (int s = 0; s < 8; ++s) {
            int m = s >> 2, r = s & 3;
            int v = n0 + wv * 32 + m * 16 + q4 * 4 + r;
            keys[slice * NVEC + v] = ((u64)__float_as_uint(s1[s]) << 32) | (unsigned)code[s];
            b2s[slice * NVEC + v]  = sb2[s];
        }
    }
}

// FUSED: slice-combine + inline exact rescue + quantized/STE/loss/counts/dw.
// Per block of 64 vectors: pick idx from the 2 slice keys; vectors with
// union margin < TAUH get a block-wide exact fp32 re-argmin (xs is already
// staged in LDS in the layout the rescan needs). ~1% of vectors flagged.
__global__ void __launch_bounds__(256)
assign_kernel(const float* __restrict__ x, const float* __restrict__ w,
              const float* __restrict__ wsqh,
              const u64* __restrict__ keys, const float* __restrict__ b2s,
              float* __restrict__ out, float* __restrict__ counts,
              float* __restrict__ dw, float* __restrict__ loss_acc) {
    __shared__ float xs[64][CDIM + 1];
    __shared__ int   sidx[64];
    __shared__ float red[256];
    __shared__ u64   rk[256];
    __shared__ unsigned fmask[2];

    int t  = threadIdx.x;
    int n0 = blockIdx.x * 64;
    int b  = n0 >> 12;
    int hw0 = n0 & (HWDIM - 1);
    const float* xbase = x + b * CHW + hw0;

    if (t < 2) fmask[t] = 0;
    __syncthreads();

    if (t < 64) {
        int n = n0 + t;
        u64 ka = keys[n], kb = keys[NVEC + n];
        u64 km = ka < kb ? ka : kb;        // equal packed score -> lower code wins
        sidx[t] = (int)(km & 0xFFFFFFFFu);
        float a1 = __uint_as_float((unsigned)(ka >> 32));   // biased > 0: bits monotone
        float c1 = __uint_as_float((unsigned)(kb >> 32));
        float lo = fminf(a1, c1), hi = fmaxf(a1, c1);
        float m2 = fminf(fminf(b2s[n], b2s[NVEC + n]), hi); // union second-best
        if (m2 - lo < TAUH) atomicOr(&fmask[t >> 5], 1u << (t & 31));
    }

    int lane = t & 63, wv = t >> 6;
#pragma unroll
    for (int j = 0; j < 16; ++j) {
        int c = wv + j * 4;
        xs[lane][c] = xbase[c * HWDIM + lane];
    }
    __syncthreads();

    // inline exact rescue (rare). Uniform control flow: fmask is shared.
    for (int h = 0; h < 2; ++h) {
        unsigned m = fmask[h];
        while (m) {
            int v = __ffs(m) - 1; m &= m - 1;
            int vv = h * 32 + v;
            u64 local = ~0ull;
            for (int k = t; k < NUM_K; k += 256) {
                const float* wr = w + k * CDIM;
                float d0 = 0.f, d1 = 0.f, d2 = 0.f, d3 = 0.f;
#pragma unroll
                for (int c = 0; c < CDIM; c += 4) {
                    d0 = fmaf(xs[vv][c + 0], wr[c + 0], d0);
                    d1 = fmaf(xs[vv][c + 1], wr[c + 1], d1);
                    d2 = fmaf(xs[vv][c + 2], wr[c + 2], d2);
                    d3 = fmaf(xs[vv][c + 3], wr[c + 3], d3);
                }
                float s = wsqh[k] - ((d0 + d1) + (d2 + d3));  // biased, exact fp32
                u64 key = ((u64)f2ord(s) << 32) | (unsigned)k; // lower k wins ties
                local = local < key ? local : key;
            }
            rk[t] = local;
            __syncthreads();
            for (int st = 128; st > 0; st >>= 1) {
                if (t < st) rk[t] = rk[t] < rk[t + st] ? rk[t] : rk[t + st];
                __syncthreads();
            }
            if (t == 0) sidx[vv] = (int)(rk[0] & 0xFFFFFFFFu);
            __syncthreads();
        }
    }

    if (t < 64) {
        out[O_IDX + n0 + t] = (float)sidx[t];
        atomicAdd(&counts[sidx[t]], 1.0f);
    }

    float lsum = 0.f;
#pragma unroll
    for (int j = 0; j < 16; ++j) {
        int c = wv + j * 4;
        float xv = xs[lane][c];
        float qv = w[sidx[lane] * CDIM + c];   // gather; codebook L2-hot (1 MB)
        float d = qv - xv;
        out[O_Q + b * CHW + c * HWDIM + hw0 + lane] = xv + d;  // STE as reference
        lsum = fmaf(d, d, lsum);
    }
    red[t] = lsum;
    __syncthreads();
    for (int st = 128; st > 0; st >>= 1) {
        if (t < st) red[t] += red[t + st];
        __syncthreads();
    }
    if (t == 0) atomicAdd(loss_acc, red[0]);

    for (int i = 0; i < 16; ++i) {
        int nl = wv * 16 + i;
        atomicAdd(&dw[sidx[nl] * CDIM + lane], xs[nl][lane]);  // wave-coalesced row
    }
}

// One fused elementwise pass over [4096,64]: new_cluster_size, new_ema_w,
// new_weight, loss. n = 0.99*sum(ecs) + 0.01*65536 (counts sum analytically).
// dw aliases out[O_EW..]: read dw[e] then overwrite with ew (per-thread RAW).
__global__ void __launch_bounds__(256)
finalize_all(const float* __restrict__ ecs, const float* __restrict__ counts,
             const float* __restrict__ ema_w, const float* __restrict__ dw,
             const float* __restrict__ loss_acc, const float* __restrict__ esum,
             float* __restrict__ out) {
    int e = blockIdx.x * 256 + threadIdx.x;   // 0..262143
    int k = e >> 6;                            // wave-uniform
    float ncs = 0.99f * ecs[k] + 0.01f * counts[k];
    if ((e & 63) == 0) out[O_CS + k] = ncs;
    if (e == 0) out[O_LOSS] = 0.25f * loss_acc[0] / 4194304.0f;
    float n = 0.99f * esum[0] + 0.01f * 65536.0f;
    float cs = (ncs + 1e-5f) / (n + NUM_K * 1e-5f) * n;
    float ew = 0.99f * ema_w[e] + 0.01f * dw[e];
    out[O_EW + e] = ew;
    out[O_W + e] = ew / cs;
}

extern "C" void kernel_launch(void* const* d_in, const int* in_sizes, int n_in,
                              void* d_out, int out_size, void* d_ws, size_t ws_size,
                              hipStream_t stream) {
    const float* x     = (const float*)d_in[0];
    const float* w     = (const float*)d_in[1];
    const float* ecs   = (const float*)d_in[2];
    const float* ema_w = (const float*)d_in[3];
    float* out = (float*)d_out;
    float* ws  = (float*)d_ws;

    float* wsqh   = ws + W_WSQ;
    float* counts = ws + W_CNT;
    float* loss_a = ws + W_LOSS;
    float* esum   = ws + W_ESUM;
    u64*   keys   = (u64*)(ws + W_KEY);
    float* b2s    = ws + W_B2;
    float* dwp    = out + O_EW;            // dw accumulator aliases new_ema_w output

    // bf16 hi/lo codebook scratch in the O_Q region (overwritten by assign)
    __bf16* wh = (__bf16*)out;
    __bf16* wl = wh + NUM_K * CDIM;

    prep_kernel<<<NUM_K / 4, 256, 0, stream>>>(w, wsqh, wh, wl, counts, dwp, ecs, esum);
    argmin_mfma<<<dim3(NVEC / 128, 2), 256, 33792, stream>>>(x, wh, wl, wsqh, keys, b2s);
    assign_kernel<<<NVEC / 64, 256, 0, stream>>>(x, w, wsqh, keys, b2s, out, counts, dwp, loss_a);
    finalize_all<<<CHW / 256, 256, 0, stream>>>(ecs, counts, ema_w, dwp, loss_a, esum, out);
}